// Round 2
// baseline (737.047 us; speedup 1.0000x reference)
//
#include <hip/hip_runtime.h>
#include <math.h>

typedef __attribute__((ext_vector_type(8))) short short8;
typedef __attribute__((ext_vector_type(4))) float float4v;

#define AST 136   // activation row stride (bf16 elems) for 128-wide buffers
#define CST 424   // cat row stride (bf16 elems), 416 padded, 848B = 16B-aligned

__device__ __forceinline__ unsigned short f2bf(float f) {
    union { float f; unsigned u; } v; v.f = f;
    return (unsigned short)((v.u + 0x7fffu + ((v.u >> 16) & 1u)) >> 16);
}
__device__ __forceinline__ float bf2f(unsigned v) {
    union { unsigned u; float f; } x; x.u = v << 16; return x.f;
}

// ---------------------------------------------------------------------------
// N-split MFMA layer, SWAPPED operands: D = W'·X' so D[outdim][node].
// Lane then holds node = lane&15 (col), outdim = q*4+r (row regs) -> the 4
// acc regs are CONTIGUOUS in the LDS row -> b64 stores instead of 4x b16.
// Loads are identical to the unswapped version (A/B fragment layouts are
// symmetric: lane&15 -> 16-dim, (lane>>4)*8 -> k).
// ---------------------------------------------------------------------------
template<int KP>
__device__ __forceinline__ void layer2t(const unsigned short* X, int astr,
                                        const unsigned short* __restrict__ WT,
                                        const float* __restrict__ bias,
                                        int lane, int tb, float4v acc[4][2])
{
    const int col0 = lane & 15, q = lane >> 4;
#pragma unroll
    for (int t = 0; t < 2; ++t) {
        // per-reg bias: outdim = (tb+t)*16 + q*4 + r
        const float4 b4 = *(const float4*)(bias + (tb + t) * 16 + q * 4);
#pragma unroll
        for (int mt = 0; mt < 4; ++mt) acc[mt][t] = (float4v){b4.x, b4.y, b4.z, b4.w};
    }
#pragma unroll
    for (int ks = 0; ks < KP; ks += 32) {
        const int k0 = ks + q * 8;
        short8 Wv[2];
#pragma unroll
        for (int t = 0; t < 2; ++t)
            Wv[t] = *(const short8*)(WT + (size_t)((tb + t) * 16 + col0) * KP + k0);
#pragma unroll
        for (int mt = 0; mt < 4; ++mt) {
            short8 Xv = *(const short8*)(X + (mt * 16 + col0) * astr + k0);
#pragma unroll
            for (int t = 0; t < 2; ++t)
                acc[mt][t] = __builtin_amdgcn_mfma_f32_16x16x32_bf16(Wv[t], Xv, acc[mt][t], 0, 0, 0);
        }
    }
}

// D layout (swapped): node = mt*16 + col0, outdim = (tb+t)*16 + q*4 + r
// -> pack the 4 regs into one ds_write_b64 at Y[node][outdim0]
__device__ __forceinline__ void store2t(float4v acc[4][2], unsigned short* Y,
                                        int lane, int tb, bool relu)
{
    const int col0 = lane & 15, q = lane >> 4;
#pragma unroll
    for (int mt = 0; mt < 4; ++mt)
#pragma unroll
        for (int t = 0; t < 2; ++t) {
            float v0 = acc[mt][t][0], v1 = acc[mt][t][1];
            float v2 = acc[mt][t][2], v3 = acc[mt][t][3];
            if (relu) {
                v0 = fmaxf(v0, 0.0f); v1 = fmaxf(v1, 0.0f);
                v2 = fmaxf(v2, 0.0f); v3 = fmaxf(v3, 0.0f);
            }
            uint2 w;
            w.x = (unsigned)f2bf(v0) | ((unsigned)f2bf(v1) << 16);
            w.y = (unsigned)f2bf(v2) | ((unsigned)f2bf(v3) << 16);
            *(uint2*)(Y + (mt * 16 + col0) * AST + (tb + t) * 16 + q * 4) = w;
        }
}

// ---------------------------------------------------------------------------
// weight prep: fp32 [K][128] -> bf16 transposed [128][KP] (zero k-padding)
// ---------------------------------------------------------------------------
__global__ void prep_kernel(const float* __restrict__ W_in, const float* __restrict__ W_g1,
                            const float* __restrict__ W_g2, const float* __restrict__ W_m1,
                            const float* __restrict__ W_m2, const float* __restrict__ W_out,
                            const float* __restrict__ W_attn, unsigned short* __restrict__ wt)
{
    int i = blockIdx.x * 256 + threadIdx.x;
    unsigned short* WT_in = wt;                 // [128][96]
    unsigned short* WT_g1 = WT_in + 12288;      // [128][128]
    unsigned short* WT_g2 = WT_g1 + 16384;      // [128][128]
    unsigned short* WT_m1 = WT_g2 + 16384;      // [128][416]
    unsigned short* WT_m2 = WT_m1 + 53248;      // [128][128]
    unsigned short* WT_h  = WT_m2 + 16384;      // [32][128]
    if (i < 12288) { int n = i / 96, k = i - n * 96;
        WT_in[i] = (k < 86) ? f2bf(W_in[k * 128 + n]) : 0; return; }
    i -= 12288;
    if (i < 16384) { int n = i >> 7, k = i & 127;
        WT_g1[i] = f2bf(W_g1[k * 128 + n]); return; }
    i -= 16384;
    if (i < 16384) { int n = i >> 7, k = i & 127;
        WT_g2[i] = f2bf(W_g2[k * 128 + n]); return; }
    i -= 16384;
    if (i < 53248) { int n = i / 416, k = i - n * 416;
        WT_m1[i] = (k < 397) ? f2bf(W_m1[k * 128 + n]) : 0; return; }
    i -= 53248;
    if (i < 16384) { int n = i >> 7, k = i & 127;
        WT_m2[i] = f2bf(W_m2[k * 128 + n]); return; }
    i -= 16384;
    if (i < 4096) { int n = i >> 7, k = i & 127;
        WT_h[i] = (n < 13) ? f2bf(W_out[k * 13 + n])
                           : (n < 26 ? f2bf(W_attn[k * 13 + (n - 13)]) : 0); }
}

// ---------------------------------------------------------------------------
// root encoder (fp32, tiny)
// ---------------------------------------------------------------------------
__global__ void root_kernel(const float* __restrict__ root_repr,
                            const float* __restrict__ W_root,
                            const float* __restrict__ b_root,
                            float* __restrict__ root_emb)
{
    __shared__ float x[86];
    const int r = blockIdx.x, tid = threadIdx.x;  // 128
    if (tid < 86) x[tid] = root_repr[(size_t)r * 86 + tid];
    __syncthreads();
    float acc = b_root[tid];
    for (int k = 0; k < 86; ++k)
        acc = fmaf(x[k], W_root[k * 128 + tid], acc);
    root_emb[(size_t)r * 128 + tid] = fmaxf(acc, 0.0f);
}

// ---------------------------------------------------------------------------
// node pipeline: 1 block = 1 strip of 64 nodes; 4 waves, each owns 2 n-tiles.
// X/Y ping-pong in LDS (34.8 KB/block -> 4 blocks/CU = 16 waves/CU).
// Reduction: 8-row octs x 4-col groups, b64 prefetch; interior runs = plain
// stores, boundary runs = atomics.
// ---------------------------------------------------------------------------
__global__ __launch_bounds__(256, 4)
void node_kernel(const float* __restrict__ node_h, const int* __restrict__ seg_ids,
                 const unsigned short* __restrict__ WT_in, const float* __restrict__ b_in,
                 const unsigned short* __restrict__ WT_g1, const float* __restrict__ b_g1,
                 const unsigned short* __restrict__ WT_g2, const float* __restrict__ b_g2,
                 float* __restrict__ frag_sum, float* __restrict__ frag_cnt)
{
    __shared__ __align__(16) unsigned short X[64 * AST];
    __shared__ __align__(16) unsigned short Y[64 * AST];
    __shared__ int segs[64];
    const int tid = threadIdx.x, wv = tid >> 6, lane = tid & 63, tb = wv * 2;
    const long n0 = (long)blockIdx.x * 64;

    if (tid < 64) segs[tid] = seg_ids[n0 + tid];
    // stage x: 64 rows x 86 fp32 (contiguous 1376 float4) -> bf16 LDS
    {
        const float4* src = (const float4*)(node_h + n0 * 86);
#pragma unroll
        for (int j = 0; j < 6; ++j) {
            int i4 = j * 256 + tid;
            if (i4 < 1376) {
                float4 v = src[i4];
                int e = i4 << 2;
                int n = e / 86, k = e - n * 86;
                X[n * AST + k] = f2bf(v.x);
                int e1 = e + 1; n = e1 / 86; k = e1 - n * 86; X[n * AST + k] = f2bf(v.y);
                int e2 = e + 2; n = e2 / 86; k = e2 - n * 86; X[n * AST + k] = f2bf(v.z);
                int e3 = e + 3; n = e3 / 86; k = e3 - n * 86; X[n * AST + k] = f2bf(v.w);
            }
        }
        for (int idx = tid; idx < 640; idx += 256) {
            int n = idx / 10, k = idx - n * 10;
            X[n * AST + 86 + k] = 0;
        }
    }
    __syncthreads();

    float4v acc[4][2];
    layer2t<96>(X, AST, WT_in, b_in, lane, tb, acc);
    store2t(acc, Y, lane, tb, false);          // layer 1: NO relu
    __syncthreads();
    layer2t<128>(Y, AST, WT_g1, b_g1, lane, tb, acc);
    store2t(acc, X, lane, tb, true);
    __syncthreads();
    layer2t<128>(X, AST, WT_g2, b_g2, lane, tb, acc);
    store2t(acc, Y, lane, tb, true);           // h3 in Y
    __syncthreads();

    // reduction: thread = (colgroup cg of 4 cols, oct of 8 rows); b64 reads
    {
        const int cg = tid & 31, oct = tid >> 5;
        const int col = cg * 4, r0 = oct * 8;
        ushort4 raw[8];
#pragma unroll
        for (int i = 0; i < 8; ++i)
            raw[i] = *(const ushort4*)(Y + (r0 + i) * AST + col);
        const int prevSeg = (oct > 0) ? segs[r0 - 1] : -1;
        const int nextSeg = (oct < 7) ? segs[r0 + 8] : -1;
        int cur = segs[r0], runStart = r0;
        float s0 = 0.f, s1 = 0.f, s2 = 0.f, s3 = 0.f, cnt = 0.f;
#pragma unroll
        for (int i = 0; i < 8; ++i) {
            const int n = r0 + i;
            int sg = segs[n];
            if (sg != cur) {
                bool bnd = (runStart == r0) && (oct == 0 || prevSeg == cur);
                float* dst = &frag_sum[(size_t)cur * 128 + col];
                if (bnd) { atomicAdd(dst, s0); atomicAdd(dst + 1, s1);
                           atomicAdd(dst + 2, s2); atomicAdd(dst + 3, s3); }
                else     { dst[0] = s0; dst[1] = s1; dst[2] = s2; dst[3] = s3; }
                if (cg == 0) {
                    if (bnd) atomicAdd(&frag_cnt[cur], cnt);
                    else     frag_cnt[cur] = cnt;
                }
                s0 = s1 = s2 = s3 = 0.f; cnt = 0.f; cur = sg; runStart = n;
            }
            s0 += bf2f(raw[i].x); s1 += bf2f(raw[i].y);
            s2 += bf2f(raw[i].z); s3 += bf2f(raw[i].w);
            cnt += 1.f;
        }
        bool bnd = ((runStart == r0) && (oct == 0 || prevSeg == cur))
                   || (oct == 7) || (nextSeg == cur);
        float* dst = &frag_sum[(size_t)cur * 128 + col];
        if (bnd) { atomicAdd(dst, s0); atomicAdd(dst + 1, s1);
                   atomicAdd(dst + 2, s2); atomicAdd(dst + 3, s3); }
        else     { dst[0] = s0; dst[1] = s1; dst[2] = s2; dst[3] = s3; }
        if (cg == 0) {
            if (bnd) atomicAdd(&frag_cnt[cur], cnt);
            else     frag_cnt[cur] = cnt;
        }
    }
}

// ---------------------------------------------------------------------------
// fragment MLP + heads: 1 block = 64 frags; cat staged in LDS, N-split waves.
// ---------------------------------------------------------------------------
__global__ __launch_bounds__(256, 2)
void frag_kernel(const float* __restrict__ root_emb, const float* __restrict__ frag_sum,
                 const float* __restrict__ frag_cnt, const int* __restrict__ ind_maps,
                 const int* __restrict__ broken,
                 const unsigned short* __restrict__ WT_m1, const float* __restrict__ b_m1,
                 const unsigned short* __restrict__ WT_m2, const float* __restrict__ b_m2,
                 const unsigned short* __restrict__ WT_h,
                 const float* __restrict__ b_out, const float* __restrict__ b_attn,
                 float* __restrict__ out0, float* __restrict__ out1)
{
    __shared__ __align__(16) unsigned short cat[64 * CST];   // 54,272 B
    __shared__ __align__(16) unsigned short Y[64 * AST];     // 17,408 B
    unsigned short* X2 = cat;                                // h2 reuses cat
    const int tid = threadIdx.x, wv = tid >> 6, lane = tid & 63, tb = wv * 2;
    const int col0 = lane & 15, q = lane >> 4;
    const long f0 = (long)blockIdx.x * 64;

    // build cat: row m = tid>>2, thread j = tid&3 covers k in [32j, 32j+32)
    {
        const int m = tid >> 2, j = tid & 3;
        int fc = (int)f0 + m; if (fc > 99999) fc = 99999;
        const int rid = ind_maps[fc];
        const float inv = 1.0f / fmaxf(frag_cnt[fc], 1.0f);
        unsigned short* row = cat + m * CST;
#pragma unroll
        for (int jj = 0; jj < 8; ++jj) {
            int k = j * 32 + jj * 4;
            float4 e = *(const float4*)(root_emb + (size_t)rid * 128 + k);
            float4 s = *(const float4*)(frag_sum + (size_t)fc * 128 + k);
            float sx = s.x * inv, sy = s.y * inv, sz = s.z * inv, sw = s.w * inv;
            uint2 w;
            w.x = (unsigned)f2bf(e.x) | ((unsigned)f2bf(e.y) << 16);
            w.y = (unsigned)f2bf(e.z) | ((unsigned)f2bf(e.w) << 16);
            *(uint2*)(row + k) = w;
            w.x = (unsigned)f2bf(e.x - sx) | ((unsigned)f2bf(e.y - sy) << 16);
            w.y = (unsigned)f2bf(e.z - sz) | ((unsigned)f2bf(e.w - sw) << 16);
            *(uint2*)(row + 128 + k) = w;
            w.x = (unsigned)f2bf(sx) | ((unsigned)f2bf(sy) << 16);
            w.y = (unsigned)f2bf(sz) | ((unsigned)f2bf(sw) << 16);
            *(uint2*)(row + 256 + k) = w;
        }
        if (j == 3) {
            int b = broken[fc]; b = b < 0 ? 0 : (b > 12 ? 12 : b);
#pragma unroll
            for (int kk = 0; kk < 32; kk += 4) {
                uint2 w;
                w.x = ((kk     == b) ? 0x3f80u : 0u) | (((kk + 1 == b) ? 0x3f80u : 0u) << 16);
                w.y = ((kk + 2 == b) ? 0x3f80u : 0u) | (((kk + 3 == b) ? 0x3f80u : 0u) << 16);
                *(uint2*)(row + 384 + kk) = w;
            }
        }
    }
    __syncthreads();

    float4v acc[4][2];
    layer2t<416>(cat, CST, WT_m1, b_m1, lane, tb, acc);
    store2t(acc, Y, lane, tb, true);           // h1
    __syncthreads();
    layer2t<128>(Y, AST, WT_m2, b_m2, lane, tb, acc);
    store2t(acc, X2, lane, tb, true);          // h2 (overwrites cat area)
    __syncthreads();

    // heads (swapped): wave wv = frag-tile; lane: ff = f0+wv*16+col0,
    // cc = t*16 + q*4 + r
    float4v hacc[2];
#pragma unroll
    for (int t = 0; t < 2; ++t) {
        const int cc0 = t * 16 + q * 4;
#pragma unroll
        for (int r = 0; r < 4; ++r) {
            int c = cc0 + r;
            hacc[t][r] = c < 13 ? b_out[c] : (c < 26 ? b_attn[c - 13] : 0.0f);
        }
    }
#pragma unroll
    for (int ks = 0; ks < 128; ks += 32) {
        const int k0 = ks + q * 8;
        short8 Xv = *(const short8*)(X2 + (wv * 16 + col0) * AST + k0);
#pragma unroll
        for (int t = 0; t < 2; ++t) {
            short8 Hv = *(const short8*)(WT_h + (t * 16 + col0) * 128 + k0);
            hacc[t] = __builtin_amdgcn_mfma_f32_16x16x32_bf16(Hv, Xv, hacc[t], 0, 0, 0);
        }
    }
    {
        const long ff = f0 + wv * 16 + col0;
        if (ff < 100000) {
#pragma unroll
            for (int t = 0; t < 2; ++t)
#pragma unroll
                for (int r = 0; r < 4; ++r) {
                    int cc = t * 16 + q * 4 + r;
                    float v = hacc[t][r];
                    if (cc < 13)      out0[ff * 13 + cc] = 1.0f / (1.0f + expf(-v));
                    else if (cc < 26) out1[ff * 13 + cc - 13] = v;
                }
        }
    }
}

extern "C" void kernel_launch(void* const* d_in, const int* in_sizes, int n_in,
                              void* d_out, int out_size, void* d_ws, size_t ws_size,
                              hipStream_t stream)
{
    const float* node_h    = (const float*)d_in[0];
    const int*   seg_ids   = (const int*)d_in[1];
    const float* root_repr = (const float*)d_in[2];
    const int*   ind_maps  = (const int*)d_in[3];
    const int*   broken    = (const int*)d_in[4];
    const float* W_root = (const float*)d_in[5];  const float* b_root = (const float*)d_in[6];
    const float* W_in   = (const float*)d_in[7];  const float* b_in   = (const float*)d_in[8];
    const float* W_g1   = (const float*)d_in[9];  const float* b_g1   = (const float*)d_in[10];
    const float* W_g2   = (const float*)d_in[11]; const float* b_g2   = (const float*)d_in[12];
    const float* W_m1   = (const float*)d_in[13]; const float* b_m1   = (const float*)d_in[14];
    const float* W_m2   = (const float*)d_in[15]; const float* b_m2   = (const float*)d_in[16];
    const float* W_out  = (const float*)d_in[17]; const float* b_out  = (const float*)d_in[18];
    const float* W_attn = (const float*)d_in[19]; const float* b_attn = (const float*)d_in[20];

    char* ws = (char*)d_ws;
    float* root_emb = (float*)ws;                          // 2000*128*4
    float* frag_sum = (float*)(ws + 1024000);              // 100000*128*4
    float* frag_cnt = (float*)(ws + 52224000);             // 100000*4
    unsigned short* wt = (unsigned short*)(ws + 52624000); // bf16 weights
    const unsigned short* WT_in = wt;
    const unsigned short* WT_g1 = wt + 12288;
    const unsigned short* WT_g2 = WT_g1 + 16384;
    const unsigned short* WT_m1 = WT_g2 + 16384;
    const unsigned short* WT_m2 = WT_m1 + 53248;
    const unsigned short* WT_h  = WT_m2 + 16384;

    hipMemsetAsync(frag_sum, 0, 51600000, stream);  // frag_sum + frag_cnt

    float* out0 = (float*)d_out;
    float* out1 = out0 + (size_t)100000 * 13;

    prep_kernel<<<464, 256, 0, stream>>>(W_in, W_g1, W_g2, W_m1, W_m2, W_out, W_attn, wt);
    root_kernel<<<2000, 128, 0, stream>>>(root_repr, W_root, b_root, root_emb);
    node_kernel<<<12500, 256, 0, stream>>>(node_h, seg_ids, WT_in, b_in,
                                           WT_g1, b_g1, WT_g2, b_g2, frag_sum, frag_cnt);
    frag_kernel<<<1563, 256, 0, stream>>>(root_emb, frag_sum, frag_cnt, ind_maps, broken,
                                          WT_m1, b_m1, WT_m2, b_m2, WT_h, b_out, b_attn,
                                          out0, out1);
}

// Round 3
// 591.175 us; speedup vs baseline: 1.2467x; 1.2467x over previous
//
#include <hip/hip_runtime.h>
#include <math.h>

typedef __attribute__((ext_vector_type(8))) short short8;
typedef __attribute__((ext_vector_type(4))) float float4v;

#define AST 136   // activation row stride (bf16 elems) for 128-wide buffers
#define CST 424   // cat row stride (bf16 elems), 416 padded, 848B = 16B-aligned

__device__ __forceinline__ unsigned short f2bf(float f) {
    union { float f; unsigned u; } v; v.f = f;
    return (unsigned short)((v.u + 0x7fffu + ((v.u >> 16) & 1u)) >> 16);
}
__device__ __forceinline__ float bf2f(unsigned v) {
    union { unsigned u; float f; } x; x.u = v << 16; return x.f;
}

// ---------------------------------------------------------------------------
// W-fragment register prefetch: this wave's 2 n-tiles, all k-steps of a layer.
// Issued BEFORE the preceding __syncthreads so L2 latency hides under the
// store + barrier drain. KP<=128 only (<=32 VGPRs).
// ---------------------------------------------------------------------------
template<int KP>
__device__ __forceinline__ void loadW(const unsigned short* __restrict__ WT,
                                      int lane, int tb, short8 Wv[2][KP / 32])
{
    const int col0 = lane & 15, q = lane >> 4;
#pragma unroll
    for (int t = 0; t < 2; ++t)
#pragma unroll
        for (int ksi = 0; ksi < KP / 32; ++ksi)
            Wv[t][ksi] = *(const short8*)(WT + (size_t)((tb + t) * 16 + col0) * KP
                                          + ksi * 32 + q * 8);
}

// MFMA layer with preloaded W regs: pure LDS-read + MFMA k-loop (round-0
// orientation: A = X-fragment, B = W-fragment, D[row=node][col=outdim]).
template<int KP, int MT>
__device__ __forceinline__ void layerP(const unsigned short* X, int astr,
                                       const float* __restrict__ bias,
                                       int lane, int tb,
                                       const short8 Wv[2][KP / 32], float4v acc[MT][2])
{
    const int col0 = lane & 15, q = lane >> 4;
#pragma unroll
    for (int t = 0; t < 2; ++t) {
        float b = bias[(tb + t) * 16 + col0];
#pragma unroll
        for (int mt = 0; mt < MT; ++mt) acc[mt][t] = (float4v){b, b, b, b};
    }
#pragma unroll
    for (int ksi = 0; ksi < KP / 32; ++ksi) {
        const int k0 = ksi * 32 + q * 8;
#pragma unroll
        for (int mt = 0; mt < MT; ++mt) {
            short8 A = *(const short8*)(X + (mt * 16 + col0) * astr + k0);
#pragma unroll
            for (int t = 0; t < 2; ++t)
                acc[mt][t] = __builtin_amdgcn_mfma_f32_16x16x32_bf16(A, Wv[t][ksi], acc[mt][t], 0, 0, 0);
        }
    }
}

// MFMA layer with in-loop global W loads (for KP=416 where regs don't fit).
template<int KP, int MT>
__device__ __forceinline__ void layerG(const unsigned short* X, int astr,
                                       const unsigned short* __restrict__ WT,
                                       const float* __restrict__ bias,
                                       int lane, int tb, float4v acc[MT][2])
{
    const int col0 = lane & 15, q = lane >> 4;
#pragma unroll
    for (int t = 0; t < 2; ++t) {
        float b = bias[(tb + t) * 16 + col0];
#pragma unroll
        for (int mt = 0; mt < MT; ++mt) acc[mt][t] = (float4v){b, b, b, b};
    }
#pragma unroll
    for (int ks = 0; ks < KP; ks += 32) {
        const int k0 = ks + q * 8;
        short8 B[2];
#pragma unroll
        for (int t = 0; t < 2; ++t)
            B[t] = *(const short8*)(WT + (size_t)((tb + t) * 16 + col0) * KP + k0);
#pragma unroll
        for (int mt = 0; mt < MT; ++mt) {
            short8 A = *(const short8*)(X + (mt * 16 + col0) * astr + k0);
#pragma unroll
            for (int t = 0; t < 2; ++t)
                acc[mt][t] = __builtin_amdgcn_mfma_f32_16x16x32_bf16(A, B[t], acc[mt][t], 0, 0, 0);
        }
    }
}

// C/D: col = (tb+t)*16+col0, row = mt*16 + q*4 + r   (round-0 proven layout)
template<int MT>
__device__ __forceinline__ void storeP(float4v acc[MT][2], unsigned short* Y,
                                       int lane, int tb, bool relu)
{
    const int col0 = lane & 15, q = lane >> 4;
#pragma unroll
    for (int mt = 0; mt < MT; ++mt)
#pragma unroll
        for (int t = 0; t < 2; ++t)
#pragma unroll
            for (int r = 0; r < 4; ++r) {
                float v = acc[mt][t][r];
                if (relu) v = fmaxf(v, 0.0f);
                Y[(mt * 16 + q * 4 + r) * AST + (tb + t) * 16 + col0] = f2bf(v);
            }
}

// ---------------------------------------------------------------------------
// weight prep: fp32 [K][128] -> bf16 transposed [128][KP] (zero k-padding)
// ---------------------------------------------------------------------------
__global__ void prep_kernel(const float* __restrict__ W_in, const float* __restrict__ W_g1,
                            const float* __restrict__ W_g2, const float* __restrict__ W_m1,
                            const float* __restrict__ W_m2, const float* __restrict__ W_out,
                            const float* __restrict__ W_attn, unsigned short* __restrict__ wt)
{
    int i = blockIdx.x * 256 + threadIdx.x;
    unsigned short* WT_in = wt;                 // [128][96]
    unsigned short* WT_g1 = WT_in + 12288;      // [128][128]
    unsigned short* WT_g2 = WT_g1 + 16384;      // [128][128]
    unsigned short* WT_m1 = WT_g2 + 16384;      // [128][416]
    unsigned short* WT_m2 = WT_m1 + 53248;      // [128][128]
    unsigned short* WT_h  = WT_m2 + 16384;      // [32][128]
    if (i < 12288) { int n = i / 96, k = i - n * 96;
        WT_in[i] = (k < 86) ? f2bf(W_in[k * 128 + n]) : 0; return; }
    i -= 12288;
    if (i < 16384) { int n = i >> 7, k = i & 127;
        WT_g1[i] = f2bf(W_g1[k * 128 + n]); return; }
    i -= 16384;
    if (i < 16384) { int n = i >> 7, k = i & 127;
        WT_g2[i] = f2bf(W_g2[k * 128 + n]); return; }
    i -= 16384;
    if (i < 53248) { int n = i / 416, k = i - n * 416;
        WT_m1[i] = (k < 397) ? f2bf(W_m1[k * 128 + n]) : 0; return; }
    i -= 53248;
    if (i < 16384) { int n = i >> 7, k = i & 127;
        WT_m2[i] = f2bf(W_m2[k * 128 + n]); return; }
    i -= 16384;
    if (i < 4096) { int n = i >> 7, k = i & 127;
        WT_h[i] = (n < 13) ? f2bf(W_out[k * 13 + n])
                           : (n < 26 ? f2bf(W_attn[k * 13 + (n - 13)]) : 0); }
}

// ---------------------------------------------------------------------------
// root encoder (fp32, tiny)
// ---------------------------------------------------------------------------
__global__ void root_kernel(const float* __restrict__ root_repr,
                            const float* __restrict__ W_root,
                            const float* __restrict__ b_root,
                            float* __restrict__ root_emb)
{
    __shared__ float x[86];
    const int r = blockIdx.x, tid = threadIdx.x;  // 128
    if (tid < 86) x[tid] = root_repr[(size_t)r * 86 + tid];
    __syncthreads();
    float acc = b_root[tid];
    for (int k = 0; k < 86; ++k)
        acc = fmaf(x[k], W_root[k * 128 + tid], acc);
    root_emb[(size_t)r * 128 + tid] = fmaxf(acc, 0.0f);
}

// ---------------------------------------------------------------------------
// node pipeline: 1 block = 1 strip of 64 nodes; 4 waves, each owns 2 n-tiles.
// X/Y ping-pong in LDS (34.8 KB/block -> 4 blocks/CU = 16 waves/CU).
// W fragments register-prefetched ahead of each barrier -> k-loop is pure
// LDS+MFMA. Reduction: round-0 proven 32-row halves, interior runs = plain
// stores, boundary runs = atomics.
// ---------------------------------------------------------------------------
__global__ __launch_bounds__(256, 4)
void node_kernel(const float* __restrict__ node_h, const int* __restrict__ seg_ids,
                 const unsigned short* __restrict__ WT_in, const float* __restrict__ b_in,
                 const unsigned short* __restrict__ WT_g1, const float* __restrict__ b_g1,
                 const unsigned short* __restrict__ WT_g2, const float* __restrict__ b_g2,
                 float* __restrict__ frag_sum, float* __restrict__ frag_cnt)
{
    __shared__ __align__(16) unsigned short X[64 * AST];
    __shared__ __align__(16) unsigned short Y[64 * AST];
    __shared__ int segs[64];
    const int tid = threadIdx.x, wv = tid >> 6, lane = tid & 63, tb = wv * 2;
    const long n0 = (long)blockIdx.x * 64;

    short8 W1[2][3];
    loadW<96>(WT_in, lane, tb, W1);            // in flight during staging

    if (tid < 64) segs[tid] = seg_ids[n0 + tid];
    // stage x: 64 rows x 86 fp32 (contiguous 1376 float4) -> bf16 LDS
    {
        const float4* src = (const float4*)(node_h + n0 * 86);
#pragma unroll
        for (int j = 0; j < 6; ++j) {
            int i4 = j * 256 + tid;
            if (i4 < 1376) {
                float4 v = src[i4];
                int e = i4 << 2;
                int n = e / 86, k = e - n * 86;
                X[n * AST + k] = f2bf(v.x);
                int e1 = e + 1; n = e1 / 86; k = e1 - n * 86; X[n * AST + k] = f2bf(v.y);
                int e2 = e + 2; n = e2 / 86; k = e2 - n * 86; X[n * AST + k] = f2bf(v.z);
                int e3 = e + 3; n = e3 / 86; k = e3 - n * 86; X[n * AST + k] = f2bf(v.w);
            }
        }
        for (int idx = tid; idx < 640; idx += 256) {
            int n = idx / 10, k = idx - n * 10;
            X[n * AST + 86 + k] = 0;
        }
    }
    __syncthreads();

    float4v acc[4][2];
    layerP<96, 4>(X, AST, b_in, lane, tb, W1, acc);
    short8 W2[2][4];
    loadW<128>(WT_g1, lane, tb, W2);           // hide under store + barrier
    storeP<4>(acc, Y, lane, tb, false);        // layer 1: NO relu
    __syncthreads();
    layerP<128, 4>(Y, AST, b_g1, lane, tb, W2, acc);
    short8 W3[2][4];
    loadW<128>(WT_g2, lane, tb, W3);
    storeP<4>(acc, X, lane, tb, true);
    __syncthreads();
    layerP<128, 4>(X, AST, b_g2, lane, tb, W3, acc);
    storeP<4>(acc, Y, lane, tb, true);         // h3 in Y
    __syncthreads();

    // reduction: thread (col = tid&127, half = tid>>7) scans 32 rows
    {
        const int col = tid & 127, half = tid >> 7, r0 = half << 5;
        const int prevSeg = (half == 1) ? segs[31] : -1;
        const int nextSeg = (half == 0) ? segs[32] : -1;
        int cur = segs[r0], runStart = r0;
        float sum = 0.f, cnt = 0.f;
        for (int n = r0; n < r0 + 32; ++n) {
            int s = segs[n];
            if (s != cur) {
                bool bnd = (runStart == r0) && (half == 0 || prevSeg == cur);
                if (bnd) atomicAdd(&frag_sum[(size_t)cur * 128 + col], sum);
                else     frag_sum[(size_t)cur * 128 + col] = sum;
                if (col == 0) {
                    if (bnd) atomicAdd(&frag_cnt[cur], cnt);
                    else     frag_cnt[cur] = cnt;
                }
                sum = 0.f; cnt = 0.f; cur = s; runStart = n;
            }
            sum += bf2f((unsigned)Y[n * AST + col]);
            cnt += 1.f;
        }
        bool bnd = ((runStart == r0) && (half == 0 || prevSeg == cur))
                   || (half == 1) || (nextSeg == cur);
        if (bnd) atomicAdd(&frag_sum[(size_t)cur * 128 + col], sum);
        else     frag_sum[(size_t)cur * 128 + col] = sum;
        if (col == 0) {
            if (bnd) atomicAdd(&frag_cnt[cur], cnt);
            else     frag_cnt[cur] = cnt;
        }
    }
}

// ---------------------------------------------------------------------------
// fragment MLP + heads: 1 block = 32 frags (was 64): LDS 35.8 KB ->
// 4 blocks/CU (was 2), grid 3125 (was 1563). Same math/layout as round 0.
// ---------------------------------------------------------------------------
__global__ __launch_bounds__(256, 4)
void frag_kernel(const float* __restrict__ root_emb, const float* __restrict__ frag_sum,
                 const float* __restrict__ frag_cnt, const int* __restrict__ ind_maps,
                 const int* __restrict__ broken,
                 const unsigned short* __restrict__ WT_m1, const float* __restrict__ b_m1,
                 const unsigned short* __restrict__ WT_m2, const float* __restrict__ b_m2,
                 const unsigned short* __restrict__ WT_h,
                 const float* __restrict__ b_out, const float* __restrict__ b_attn,
                 float* __restrict__ out0, float* __restrict__ out1)
{
    __shared__ __align__(16) unsigned short cat[32 * CST];   // 27,136 B
    __shared__ __align__(16) unsigned short Y[32 * AST];     //  8,704 B
    unsigned short* X2 = cat;                                // h2 reuses cat
    const int tid = threadIdx.x, wv = tid >> 6, lane = tid & 63, tb = wv * 2;
    const int col0 = lane & 15, q = lane >> 4;
    const long f0 = (long)blockIdx.x * 32;

    // build cat: row m = tid>>3 (32 rows), thread j = tid&7 covers k in [16j,16j+16)
    {
        const int m = tid >> 3, j = tid & 7;
        int fc = (int)f0 + m; if (fc > 99999) fc = 99999;
        const int rid = ind_maps[fc];
        const float inv = 1.0f / fmaxf(frag_cnt[fc], 1.0f);
        unsigned short* row = cat + m * CST;
#pragma unroll
        for (int jj = 0; jj < 4; ++jj) {
            int k = j * 16 + jj * 4;
            float4 e = *(const float4*)(root_emb + (size_t)rid * 128 + k);
            float4 s = *(const float4*)(frag_sum + (size_t)fc * 128 + k);
            float sx = s.x * inv, sy = s.y * inv, sz = s.z * inv, sw = s.w * inv;
            uint2 w;
            w.x = (unsigned)f2bf(e.x) | ((unsigned)f2bf(e.y) << 16);
            w.y = (unsigned)f2bf(e.z) | ((unsigned)f2bf(e.w) << 16);
            *(uint2*)(row + k) = w;
            w.x = (unsigned)f2bf(e.x - sx) | ((unsigned)f2bf(e.y - sy) << 16);
            w.y = (unsigned)f2bf(e.z - sz) | ((unsigned)f2bf(e.w - sw) << 16);
            *(uint2*)(row + 128 + k) = w;
            w.x = (unsigned)f2bf(sx) | ((unsigned)f2bf(sy) << 16);
            w.y = (unsigned)f2bf(sz) | ((unsigned)f2bf(sw) << 16);
            *(uint2*)(row + 256 + k) = w;
        }
        if (j == 7) {
            int b = broken[fc]; b = b < 0 ? 0 : (b > 12 ? 12 : b);
#pragma unroll
            for (int kk = 0; kk < 32; kk += 4) {
                uint2 w;
                w.x = ((kk     == b) ? 0x3f80u : 0u) | (((kk + 1 == b) ? 0x3f80u : 0u) << 16);
                w.y = ((kk + 2 == b) ? 0x3f80u : 0u) | (((kk + 3 == b) ? 0x3f80u : 0u) << 16);
                *(uint2*)(row + 384 + kk) = w;
            }
        }
    }
    __syncthreads();

    float4v acc[2][2];
    layerG<416, 2>(cat, CST, WT_m1, b_m1, lane, tb, acc);
    short8 Wm2[2][4];
    loadW<128>(WT_m2, lane, tb, Wm2);          // hide under store + barrier
    storeP<2>(acc, Y, lane, tb, true);         // h1
    __syncthreads();
    layerP<128, 2>(Y, AST, b_m2, lane, tb, Wm2, acc);
    // heads W prefetch: wave wv -> m-tile mrow = wv&1, n-tile t_h = wv>>1
    const int mrow = wv & 1, t_h = wv >> 1;
    short8 Wh[4];
#pragma unroll
    for (int ksi = 0; ksi < 4; ++ksi)
        Wh[ksi] = *(const short8*)(WT_h + (t_h * 16 + col0) * 128 + ksi * 32 + q * 8);
    storeP<2>(acc, X2, lane, tb, true);        // h2 (overwrites cat area)
    __syncthreads();

    // heads: K=128 from X2; out cols cc = t_h*16+col0 (26 valid)
    {
        const int cc = t_h * 16 + col0;
        float b = cc < 13 ? b_out[cc] : (cc < 26 ? b_attn[cc - 13] : 0.0f);
        float4v hacc = (float4v){b, b, b, b};
#pragma unroll
        for (int ksi = 0; ksi < 4; ++ksi) {
            short8 A = *(const short8*)(X2 + (mrow * 16 + col0) * AST + ksi * 32 + q * 8);
            hacc = __builtin_amdgcn_mfma_f32_16x16x32_bf16(A, Wh[ksi], hacc, 0, 0, 0);
        }
#pragma unroll
        for (int r = 0; r < 4; ++r) {
            long ff = f0 + mrow * 16 + q * 4 + r;
            if (ff < 100000) {
                float v = hacc[r];
                if (cc < 13)      out0[ff * 13 + cc] = 1.0f / (1.0f + expf(-v));
                else if (cc < 26) out1[ff * 13 + cc - 13] = v;
            }
        }
    }
}

extern "C" void kernel_launch(void* const* d_in, const int* in_sizes, int n_in,
                              void* d_out, int out_size, void* d_ws, size_t ws_size,
                              hipStream_t stream)
{
    const float* node_h    = (const float*)d_in[0];
    const int*   seg_ids   = (const int*)d_in[1];
    const float* root_repr = (const float*)d_in[2];
    const int*   ind_maps  = (const int*)d_in[3];
    const int*   broken    = (const int*)d_in[4];
    const float* W_root = (const float*)d_in[5];  const float* b_root = (const float*)d_in[6];
    const float* W_in   = (const float*)d_in[7];  const float* b_in   = (const float*)d_in[8];
    const float* W_g1   = (const float*)d_in[9];  const float* b_g1   = (const float*)d_in[10];
    const float* W_g2   = (const float*)d_in[11]; const float* b_g2   = (const float*)d_in[12];
    const float* W_m1   = (const float*)d_in[13]; const float* b_m1   = (const float*)d_in[14];
    const float* W_m2   = (const float*)d_in[15]; const float* b_m2   = (const float*)d_in[16];
    const float* W_out  = (const float*)d_in[17]; const float* b_out  = (const float*)d_in[18];
    const float* W_attn = (const float*)d_in[19]; const float* b_attn = (const float*)d_in[20];

    char* ws = (char*)d_ws;
    float* root_emb = (float*)ws;                          // 2000*128*4
    float* frag_sum = (float*)(ws + 1024000);              // 100000*128*4
    float* frag_cnt = (float*)(ws + 52224000);             // 100000*4
    unsigned short* wt = (unsigned short*)(ws + 52624000); // bf16 weights
    const unsigned short* WT_in = wt;
    const unsigned short* WT_g1 = wt + 12288;
    const unsigned short* WT_g2 = WT_g1 + 16384;
    const unsigned short* WT_m1 = WT_g2 + 16384;
    const unsigned short* WT_m2 = WT_m1 + 53248;
    const unsigned short* WT_h  = WT_m2 + 16384;

    hipMemsetAsync(frag_sum, 0, 51600000, stream);  // frag_sum + frag_cnt

    float* out0 = (float*)d_out;
    float* out1 = out0 + (size_t)100000 * 13;

    prep_kernel<<<464, 256, 0, stream>>>(W_in, W_g1, W_g2, W_m1, W_m2, W_out, W_attn, wt);
    root_kernel<<<2000, 128, 0, stream>>>(root_repr, W_root, b_root, root_emb);
    node_kernel<<<12500, 256, 0, stream>>>(node_h, seg_ids, WT_in, b_in,
                                           WT_g1, b_g1, WT_g2, b_g2, frag_sum, frag_cnt);
    frag_kernel<<<3125, 256, 0, stream>>>(root_emb, frag_sum, frag_cnt, ind_maps, broken,
                                          WT_m1, b_m1, WT_m2, b_m2, WT_h, b_out, b_attn,
                                          out0, out1);
}